// Round 19
// baseline (156.203 us; speedup 1.0000x reference)
//
#include <hip/hip_runtime.h>
#include <hip/hip_bf16.h>

typedef _Float16 h16;
typedef __attribute__((ext_vector_type(8))) _Float16 f16x8v;   // 8 f16 (4 VGPR)
typedef __attribute__((ext_vector_type(2))) _Float16 h2v;      // packed pair
typedef __attribute__((ext_vector_type(4))) float f32x4;       // MFMA acc
#define DI __device__ __forceinline__

constexpr int CH = 128;
constexpr int HH = 96, WW = 96;
constexpr int HW = HH * WW;          // 9216
constexpr int NB = 4;
constexpr int NPIX = NB * HW;        // 36864
constexpr int LDT = 136;             // conv LDS row stride (elems)
constexpr size_t HP = (size_t)NPIX * 32;   // head-plane elements
constexpr int GH = NPIX / 64;        // 576 conv blocks per tensor
// attention tile geometry (r10 best-measured config)
constexpr int TY = 4, TX = 32;       // tile pixels
constexpr int HYH = TY + 4, HXH = TX + 4;  // halo 8 x 36
constexpr int LDC = 40;              // LDS ch stride
constexpr int ATB = NPIX / (TY * TX) * 4;  // 1152 attn blocks per set

struct __attribute__((aligned(16))) h16x8 { h16 h[8]; };
struct Set { h16 *q, *k, *v; };      // comp-plane bases, each [4][NPIX][32]

DI float h2f(h16 x) { return (float)x; }
DI h16   f2h(float x) { return (h16)x; }

// ---- staging helpers (256 thr) --------------------------------------------

// pixel-major f16 [p][ldx] -> LDS tile [px][c]
DI void stage_x_cl(const h16* __restrict__ src, int ldx, h16* xl, int t) {
    #pragma unroll
    for (int i = 0; i < 4; ++i) {
        int id = t + 256 * i, px = id >> 4, cc = (id & 15) * 8;
        *reinterpret_cast<f16x8v*>(&xl[px * LDT + cc]) =
            *reinterpret_cast<const f16x8v*>(&src[(size_t)px * ldx + cc]);
    }
}

// planar f32 [c][HW] -> LDS tile [px][c] f16
DI void stage_x_pl(const float* __restrict__ src, h16* xl, int t) {
    #pragma unroll
    for (int i = 0; i < 8; ++i) {
        int id = t + 256 * i, c = id >> 4, p4 = (id & 15) * 4;
        float4 v = *reinterpret_cast<const float4*>(&src[(size_t)c * HW + p4]);
        xl[(p4 + 0) * LDT + c] = f2h(v.x);
        xl[(p4 + 1) * LDT + c] = f2h(v.y);
        xl[(p4 + 2) * LDT + c] = f2h(v.z);
        xl[(p4 + 3) * LDT + c] = f2h(v.w);
    }
}

// head-major T [h][p][32] -> LDS tile [px][128]
DI void stage_x_hm(const h16* __restrict__ Tq, h16* xl, int p0, int t) {
    const int px = t >> 2, c8 = (t & 3) * 8;
    #pragma unroll
    for (int h = 0; h < 4; ++h)
        *reinterpret_cast<f16x8v*>(&xl[px * LDT + h * 32 + c8]) =
            *reinterpret_cast<const f16x8v*>(&Tq[(size_t)h * HP + (size_t)(p0 + px) * 32 + c8]);
}

DI void stage_w(const float* __restrict__ w, h16* wl, int t) {
    #pragma unroll
    for (int i = 0; i < 8; ++i) {
        int id = t + 256 * i, o = id >> 4, cc = (id & 15) * 8;
        float4 a = *reinterpret_cast<const float4*>(&w[o * CH + cc]);
        float4 b = *reinterpret_cast<const float4*>(&w[o * CH + cc + 4]);
        h16x8 tmp;
        tmp.h[0] = f2h(a.x); tmp.h[1] = f2h(a.y); tmp.h[2] = f2h(a.z); tmp.h[3] = f2h(a.w);
        tmp.h[4] = f2h(b.x); tmp.h[5] = f2h(b.y); tmp.h[6] = f2h(b.z); tmp.h[7] = f2h(b.w);
        *reinterpret_cast<f16x8v*>(&wl[o * LDT + cc]) = *reinterpret_cast<const f16x8v*>(&tmp);
    }
}

// register-prefetch version of stage_w: issue loads + cvt into 32 VGPRs
DI void wload(const float* __restrict__ w, f16x8v* pre, int t) {
    #pragma unroll
    for (int i = 0; i < 8; ++i) {
        int id = t + 256 * i, o = id >> 4, cc = (id & 15) * 8;
        float4 a = *reinterpret_cast<const float4*>(&w[o * CH + cc]);
        float4 b = *reinterpret_cast<const float4*>(&w[o * CH + cc + 4]);
        h16x8 tmp;
        tmp.h[0] = f2h(a.x); tmp.h[1] = f2h(a.y); tmp.h[2] = f2h(a.z); tmp.h[3] = f2h(a.w);
        tmp.h[4] = f2h(b.x); tmp.h[5] = f2h(b.y); tmp.h[6] = f2h(b.z); tmp.h[7] = f2h(b.w);
        pre[i] = *reinterpret_cast<const f16x8v*>(&tmp);
    }
}
DI void wcommit(const f16x8v* pre, h16* wl, int t) {
    #pragma unroll
    for (int i = 0; i < 8; ++i) {
        int id = t + 256 * i, o = id >> 4, cc = (id & 15) * 8;
        *reinterpret_cast<f16x8v*>(&wl[o * LDT + cc]) = pre[i];
    }
}

// resid tile prefetch: planar f32 -> 8 float4 regs -> rl[c][65]
DI void rload(const float* __restrict__ src, float4* rpre, int t) {
    #pragma unroll
    for (int i = 0; i < 8; ++i) {
        int id = t + 256 * i, c = id >> 4, p4 = (id & 15) * 4;
        rpre[i] = *reinterpret_cast<const float4*>(&src[(size_t)c * HW + p4]);
    }
}
DI void rcommit(const float4* rpre, float* rl, int t) {
    #pragma unroll
    for (int i = 0; i < 8; ++i) {
        int id = t + 256 * i, c = id >> 4, p4 = (id & 15) * 4;
        rl[c * 65 + p4 + 0] = rpre[i].x;
        rl[c * 65 + p4 + 1] = rpre[i].y;
        rl[c * 65 + p4 + 2] = rpre[i].z;
        rl[c * 65 + p4 + 3] = rpre[i].w;
    }
}

DI void gemm64(const h16* xl, const h16* wl, int w, int l, f32x4* acc) {
    const int s = l & 15, g = l >> 4;
    #pragma unroll
    for (int ks = 0; ks < 4; ++ks) {
        f16x8v a = *reinterpret_cast<const f16x8v*>(&xl[(16 * w + s) * LDT + ks * 32 + g * 8]);
        #pragma unroll
        for (int n = 0; n < 8; ++n) {
            f16x8v b = *reinterpret_cast<const f16x8v*>(&wl[(16 * n + s) * LDT + ks * 32 + g * 8]);
            acc[n] = __builtin_amdgcn_mfma_f32_16x16x32_f16(a, b, acc[n], 0, 0, 0);
        }
    }
}

// epilogue into head-major comp plane [head][p][32]
DI void qkv_epi(const f32x4* acc, h16* comp, int p0, int w, int l) {
    const int s = l & 15, g = l >> 4;
    #pragma unroll
    for (int n = 0; n < 8; ++n) {
        const int o = 16 * n + s, head = o >> 5, ch = o & 31;
        h16* pl = comp + (size_t)head * HP;
        #pragma unroll
        for (int j = 0; j < 4; ++j) {
            int px = 16 * w + 4 * g + j;
            pl[(size_t)(p0 + px) * 32 + ch] = f2h(acc[n][j]);
        }
    }
}

// in-wave channel LayerNorm on r[8][4]; lanes sharing (l>>4) hold all 128 o.
DI void ln128(float r[8][4], const float* gm, const float* bt, float val[8][4]) {
    #pragma unroll
    for (int j = 0; j < 4; ++j) {
        float sm = 0.f, sq = 0.f;
        #pragma unroll
        for (int n = 0; n < 8; ++n) { float v = r[n][j]; sm += v; sq += v * v; }
        sm += __shfl_xor(sm, 1); sq += __shfl_xor(sq, 1);
        sm += __shfl_xor(sm, 2); sq += __shfl_xor(sq, 2);
        sm += __shfl_xor(sm, 4); sq += __shfl_xor(sq, 4);
        sm += __shfl_xor(sm, 8); sq += __shfl_xor(sq, 8);
        const float mu = sm * (1.f / 128.f);
        const float var = sq * (1.f / 128.f) - mu * mu;
        const float rs = rsqrtf(var + 1e-6f);
        #pragma unroll
        for (int n = 0; n < 8; ++n)
            val[n][j] = gm[n] * (r[n][j] - mu) * rs + bt[n];
    }
}

// ---- batched self-attn QKV (256 thr, reg-prefetched W) --------------------
__global__ __launch_bounds__(256, 2)
void qkv_self_b(const float* __restrict__ x0, const float* __restrict__ x1,
                const float* __restrict__ w0, const float* __restrict__ w1_,
                const float* __restrict__ w2_, Set sA, Set sB) {
    __shared__ h16 xl[64 * LDT];
    __shared__ h16 wl[CH * LDT];
    const int bid = blockIdx.x, half = bid / GH, p0 = (bid % GH) * 64;
    const float* xv = half ? x1 : x0;
    Set S = half ? sB : sA;
    const int t = threadIdx.x;
    const int b = p0 / HW, hw0 = p0 % HW;
    stage_x_pl(xv + (size_t)b * CH * HW + hw0, xl, t);
    stage_w(w0, wl, t);
    __syncthreads();
    const int w = t >> 6, l = t & 63;

    f16x8v pre[8];
    #pragma unroll
    for (int m = 0; m < 3; ++m) {
        h16* comp = (m == 0) ? S.q : ((m == 1) ? S.k : S.v);
        if (m == 0) wload(w1_, pre, t);        // in flight during gemm
        if (m == 1) wload(w2_, pre, t);
        f32x4 acc[8];
        #pragma unroll
        for (int n = 0; n < 8; ++n) acc[n] = {0.f, 0.f, 0.f, 0.f};
        gemm64(xl, wl, w, l, acc);
        qkv_epi(acc, comp, p0, w, l);
        if (m < 2) {
            __syncthreads();                   // wl reads done
            wcommit(pre, wl, t);
            __syncthreads();                   // wl ready
        }
    }
}

// ---- 5x5 local attention (batched over 2 sets) — r10 best config ----------
__global__ __launch_bounds__(256)
void attn5b(Set s0, Set s1) {
    __shared__ h16 kv[HYH * HXH * LDC];          // 23 KB, reused K then V
    const int bid = blockIdx.x, setId = bid / ATB, id = bid - setId * ATB;
    Set S = setId ? s1 : s0;
    const int n = id & 3, tile = id >> 2;
    const int img = tile / 72, rem = tile % 72, tr = rem / 3, tc = rem % 3;
    const int y0 = tr * TY, x0 = tc * TX;
    const int t = threadIdx.x;
    const int p = t >> 1, half = t & 1, ch16 = half * 16;
    const int ty = p >> 5, tx = p & 31;
    h16* Qh = S.q + (size_t)n * HP;
    const h16* Kh = S.k + (size_t)n * HP;
    const h16* Vh = S.v + (size_t)n * HP;
    const int gp = img * HW + (y0 + ty) * WW + (x0 + tx);
    h16* qp = Qh + (size_t)gp * 32 + ch16;

    f16x8v q0 = *reinterpret_cast<const f16x8v*>(qp);
    f16x8v q1 = *reinterpret_cast<const f16x8v*>(qp + 8);
    {
        const h16 sc = (h16)0.17677669529663689f;
        #pragma unroll
        for (int e = 0; e < 8; ++e) { q0[e] *= sc; q1[e] *= sc; }
    }

    #pragma unroll
    for (int i = 0; i < 5; ++i) {
        int id2 = t + 256 * i;
        if (id2 < 1152) {
            int r = id2 / 144, c = id2 - r * 144, px = c >> 2, c8 = (c & 3) * 8;
            int y = y0 + r - 2, x = x0 + px - 2;
            f16x8v v = {0, 0, 0, 0, 0, 0, 0, 0};
            if ((unsigned)y < (unsigned)HH && (unsigned)x < (unsigned)WW)
                v = *reinterpret_cast<const f16x8v*>(&Kh[((size_t)(img * HW + y * WW + x)) * 32 + c8]);
            *reinterpret_cast<f16x8v*>(&kv[(r * HXH + px) * LDC + c8]) = v;
        }
    }
    __syncthreads();

    float corr[25];
    #pragma unroll
    for (int dy = 0; dy < 5; ++dy)
        #pragma unroll
        for (int dx = 0; dx < 5; ++dx) {
            const h16* kp = &kv[((ty + dy) * HXH + tx + dx) * LDC + ch16];
            f16x8v k0 = *reinterpret_cast<const f16x8v*>(kp);
            f16x8v k1 = *reinterpret_cast<const f16x8v*>(kp + 8);
            float s;
#if __has_builtin(__builtin_amdgcn_fdot2)
            s = __builtin_amdgcn_fdot2(h2v{q0[0], q0[1]}, h2v{k0[0], k0[1]}, 0.f, false);
            s = __builtin_amdgcn_fdot2(h2v{q0[2], q0[3]}, h2v{k0[2], k0[3]}, s, false);
            s = __builtin_amdgcn_fdot2(h2v{q0[4], q0[5]}, h2v{k0[4], k0[5]}, s, false);
            s = __builtin_amdgcn_fdot2(h2v{q0[6], q0[7]}, h2v{k0[6], k0[7]}, s, false);
            s = __builtin_amdgcn_fdot2(h2v{q1[0], q1[1]}, h2v{k1[0], k1[1]}, s, false);
            s = __builtin_amdgcn_fdot2(h2v{q1[2], q1[3]}, h2v{k1[2], k1[3]}, s, false);
            s = __builtin_amdgcn_fdot2(h2v{q1[4], q1[5]}, h2v{k1[4], k1[5]}, s, false);
            s = __builtin_amdgcn_fdot2(h2v{q1[6], q1[7]}, h2v{k1[6], k1[7]}, s, false);
#else
            s = 0.f;
            #pragma unroll
            for (int e = 0; e < 8; ++e) s += h2f(q0[e]) * h2f(k0[e]);
            #pragma unroll
            for (int e = 0; e < 8; ++e) s += h2f(q1[e]) * h2f(k1[e]);
#endif
            s += __shfl_xor(s, 1);
            corr[dy * 5 + dx] = s;
        }

    float m = corr[0];
    #pragma unroll
    for (int j = 1; j < 25; ++j) m = fmaxf(m, corr[j]);
    float sum = 0.f;
    #pragma unroll
    for (int j = 0; j < 25; ++j) {
        float e = __expf(corr[j] - m);
        corr[j] = e; sum += e;
    }
    const float inv = 1.f / sum;

    __syncthreads();                               // all K reads done
    #pragma unroll
    for (int i = 0; i < 5; ++i) {
        int id2 = t + 256 * i;
        if (id2 < 1152) {
            int r = id2 / 144, c = id2 - r * 144, px = c >> 2, c8 = (c & 3) * 8;
            int y = y0 + r - 2, x = x0 + px - 2;
            f16x8v v = {0, 0, 0, 0, 0, 0, 0, 0};
            if ((unsigned)y < (unsigned)HH && (unsigned)x < (unsigned)WW)
                v = *reinterpret_cast<const f16x8v*>(&Vh[((size_t)(img * HW + y * WW + x)) * 32 + c8]);
            *reinterpret_cast<f16x8v*>(&kv[(r * HXH + px) * LDC + c8]) = v;
        }
    }
    __syncthreads();

    f16x8v o0 = {0, 0, 0, 0, 0, 0, 0, 0};
    f16x8v o1 = {0, 0, 0, 0, 0, 0, 0, 0};
    #pragma unroll
    for (int dy = 0; dy < 5; ++dy)
        #pragma unroll
        for (int dx = 0; dx < 5; ++dx) {
            const h16 ah = f2h(corr[dy * 5 + dx]);
            const f16x8v av = {ah, ah, ah, ah, ah, ah, ah, ah};
            const h16* vp = &kv[((ty + dy) * HXH + tx + dx) * LDC + ch16];
            f16x8v v0 = *reinterpret_cast<const f16x8v*>(vp);
            f16x8v v1 = *reinterpret_cast<const f16x8v*>(vp + 8);
            o0 += av * v0;                       // v_pk_fma_f16
            o1 += av * v1;
        }
    {
        const h16 ih = f2h(inv);
        const f16x8v iv = {ih, ih, ih, ih, ih, ih, ih, ih};
        o0 *= iv; o1 *= iv;
    }
    *reinterpret_cast<f16x8v*>(qp)     = o0;
    *reinterpret_cast<f16x8v*>(qp + 8) = o1;
}

// ---- fcx_a: fc+LN -> X (global, vectorized). Chain = 1 GEMM. --------------
__global__ __launch_bounds__(256, 2)
void fcx_a(const h16* __restrict__ tA, const h16* __restrict__ tB,
           const float* __restrict__ in1, const float* __restrict__ in2,
           const float* __restrict__ wfc, const float* __restrict__ gamma,
           const float* __restrict__ beta,
           h16* __restrict__ x1g, h16* __restrict__ x2g) {
    __shared__ h16 xl[64 * LDT];
    __shared__ __align__(16) char wsm[CH * LDT * 2];   // wl (h16) | rl (f32)
    h16*   wl = (h16*)wsm;
    float* rl = (float*)wsm;
    const int bid = blockIdx.x, half = bid / GH, p0 = (bid % GH) * 64;
    const h16*   tin = half ? tB : tA;
    const float* inr = half ? in2 : in1;
    h16*         xg  = half ? x2g : x1g;
    const int t = threadIdx.x;
    const int w = t >> 6, l = t & 63, s = l & 15, g4 = l >> 4;
    const int b = p0 / HW, hw0 = p0 % HW;

    stage_x_hm(tin, xl, p0, t);
    stage_w(wfc, wl, t);
    float4 rpre[8];
    rload(inr + (size_t)b * CH * HW + hw0, rpre, t);   // resid in flight
    __syncthreads();

    f32x4 accF[8];
    #pragma unroll
    for (int n = 0; n < 8; ++n) accF[n] = {0.f, 0.f, 0.f, 0.f};
    gemm64(xl, wl, w, l, accF);
    __syncthreads();                 // wl/xl reads done -> rl may overwrite wl

    rcommit(rpre, rl, t);
    __syncthreads();                 // rl visible

    float gm[8], bt[8], r[8][4], val[8][4];
    #pragma unroll
    for (int n = 0; n < 8; ++n) { gm[n] = gamma[16 * n + s]; bt[n] = beta[16 * n + s]; }
    #pragma unroll
    for (int n = 0; n < 8; ++n) {
        const int o = 16 * n + s;
        #pragma unroll
        for (int j = 0; j < 4; ++j)
            r[n][j] = accF[n][j] + rl[o * 65 + (16 * w + 4 * g4 + j)];
    }
    ln128(r, gm, bt, val);
    // X -> xl (xl reads done since fc GEMM barrier)
    #pragma unroll
    for (int n = 0; n < 8; ++n) {
        const int o = 16 * n + s;
        #pragma unroll
        for (int j = 0; j < 4; ++j)
            xl[(16 * w + 4 * g4 + j) * LDT + o] = f2h(val[n][j]);
    }
    __syncthreads();                 // xl(X) visible
    // vector store X (contiguous 256B per px row)
    #pragma unroll
    for (int i = 0; i < 4; ++i) {
        int id = t + 256 * i, px = id >> 4, c8 = (id & 15) * 8;
        *reinterpret_cast<f16x8v*>(&xg[(size_t)(p0 + px) * CH + c8]) =
            *reinterpret_cast<const f16x8v*>(&xl[px * LDT + c8]);
    }
}

// ---- fcx_b2: one cross-QKV GEMM per block (mvar = q/k/v). 1 barrier. ------
// mvar0: q = wq*X_own -> own set. mvar1/2: k/v = w*X_own -> OTHER set.
__global__ __launch_bounds__(256, 2)
void fcx_b2(const h16* __restrict__ x1, const h16* __restrict__ x2,
            const float* __restrict__ wq, const float* __restrict__ wk,
            const float* __restrict__ wv, Set c1, Set c2) {
    __shared__ h16 xl[64 * LDT];
    __shared__ h16 wl[CH * LDT];
    const int bid = blockIdx.x;
    const int mvar = bid / (2 * GH);
    const int rem  = bid - mvar * 2 * GH;
    const int half = rem / GH, p0 = (rem % GH) * 64;
    const h16* xs = half ? x2 : x1;
    Set own   = half ? c2 : c1;
    Set other = half ? c1 : c2;
    h16* comp = (mvar == 0) ? own.q : ((mvar == 1) ? other.k : other.v);
    const float* wm = (mvar == 0) ? wq : ((mvar == 1) ? wk : wv);
    const int t = threadIdx.x, w = t >> 6, l = t & 63;

    stage_x_cl(xs + (size_t)p0 * CH, CH, xl, t);
    stage_w(wm, wl, t);
    __syncthreads();

    f32x4 acc[8];
    #pragma unroll
    for (int n = 0; n < 8; ++n) acc[n] = {0.f, 0.f, 0.f, 0.f};
    gemm64(xl, wl, w, l, acc);
    qkv_epi(acc, comp, p0, w, l);
}

// ---- FUSED: fc+LN (cross) + full FFN + final LN -> planar f32 out ---------
__global__ __launch_bounds__(256, 2)
void ffn_ln_b(const h16* __restrict__ t0, const h16* __restrict__ t1,
              const h16* __restrict__ x0, const h16* __restrict__ x1,
              const float* __restrict__ wfc, const float* __restrict__ gc,
              const float* __restrict__ bc,
              const float* __restrict__ w1m, const float* __restrict__ b1v,
              const float* __restrict__ w2m, const float* __restrict__ b2v,
              const float* __restrict__ gf, const float* __restrict__ bf,
              float* __restrict__ o0, float* __restrict__ o1) {
    __shared__ __align__(16) char smem[64 * LDT * 2 * 2 + CH * LDT * 2]; // 69632 B
    h16*   xl = (h16*)smem;                        // T stage, later h tile
    h16*   yl = (h16*)(smem + 64 * LDT * 2);       // Y tile (resid)
    h16*   wl = (h16*)(smem + 64 * LDT * 2 * 2);   // fc_c, W1, W2 in turn
    float* ll = (float*)(smem + 64 * LDT * 2 * 2); // out bounce (aliases wl)
    const int bid = blockIdx.x, half = bid / GH, p0 = (bid % GH) * 64;
    const h16* tin = half ? t1 : t0;
    const h16* xg  = half ? x1 : x0;
    float* outp = half ? o1 : o0;
    const int t = threadIdx.x;
    const int w = t >> 6, l = t & 63, s = l & 15, g4 = l >> 4;

    stage_x_hm(tin, xl, p0, t);
    stage_w(wfc, wl, t);
    __syncthreads();

    // Y = LN(fc(T) + X)
    h16 yv[8][4];
    {
        f32x4 acc[8];
        #pragma unroll
        for (int n = 0; n < 8; ++n) acc[n] = {0.f, 0.f, 0.f, 0.f};
        gemm64(xl, wl, w, l, acc);
        float gm[8], bt[8], r[8][4], val[8][4];
        #pragma unroll
        for (int n = 0; n < 8; ++n) { gm[n] = gc[16 * n + s]; bt[n] = bc[16 * n + s]; }
        #pragma unroll
        for (int n = 0; n < 8; ++n) {
            const int o = 16 * n + s;
            #pragma unroll
            for (int j = 0; j < 4; ++j) {
                const int px = 16 * w + 4 * g4 + j;
                r[n][j] = acc[n][j] + h2f(xg[(size_t)(p0 + px) * CH + o]);
            }
        }
        ln128(r, gm, bt, val);
        #pragma unroll
        for (int n = 0; n < 8; ++n)
            #pragma unroll
            for (int j = 0; j < 4; ++j) yv[n][j] = f2h(val[n][j]);
    }
    __syncthreads();                 // xl/wl gemm reads done
    #pragma unroll
    for (int n = 0; n < 8; ++n) {
        const int o = 16 * n + s;
        #pragma unroll
        for (int j = 0; j < 4; ++j)
            yl[(16 * w + 4 * g4 + j) * LDT + o] = yv[n][j];
    }
    stage_w(w1m, wl, t);
    __syncthreads();

    // h = relu(W1 Y + b1) -> hl (reuses xl)
    {
        f32x4 acc[8];
        #pragma unroll
        for (int n = 0; n < 8; ++n) acc[n] = {0.f, 0.f, 0.f, 0.f};
        gemm64(yl, wl, w, l, acc);
        #pragma unroll
        for (int n = 0; n < 8; ++n) {
            const int o = 16 * n + s;
            const float bv = b1v[o];
            #pragma unroll
            for (int j = 0; j < 4; ++j)
                xl[(16 * w + 4 * g4 + j) * LDT + o] = f2h(fmaxf(acc[n][j] + bv, 0.f));
        }
    }
    __syncthreads();                 // wl gemm reads + hl writes done
    stage_w(w2m, wl, t);
    __syncthreads();

    // out = LN2(W2 h + b2) + Y
    float val[8][4];
    {
        f32x4 acc[8];
        #pragma unroll
        for (int n = 0; n < 8; ++n) acc[n] = {0.f, 0.f, 0.f, 0.f};
        gemm64(xl, wl, w, l, acc);
        float gm[8], bt[8], r[8][4];
        #pragma unroll
        for (int n = 0; n < 8; ++n) { gm[n] = gf[16 * n + s]; bt[n] = bf[16 * n + s]; }
        #pragma unroll
        for (int n = 0; n < 8; ++n) {
            const int o = 16 * n + s;
            const float bv = b2v[o];
            #pragma unroll
            for (int j = 0; j < 4; ++j) r[n][j] = acc[n][j] + bv;
        }
        ln128(r, gm, bt, val);
        #pragma unroll
        for (int n = 0; n < 8; ++n) {
            const int o = 16 * n + s;
            #pragma unroll
            for (int j = 0; j < 4; ++j)
                val[n][j] += h2f(yl[(16 * w + 4 * g4 + j) * LDT + o]);
        }
    }
    __syncthreads();                 // wl(gemm3)/yl reads done -> ll may alias
    #pragma unroll
    for (int n = 0; n < 8; ++n) {
        const int o = 16 * n + s;
        #pragma unroll
        for (int j = 0; j < 4; ++j) ll[o * 65 + 16 * w + 4 * g4 + j] = val[n][j];
    }
    __syncthreads();
    const int b = p0 / HW, hw0 = p0 % HW;
    #pragma unroll
    for (int i = 0; i < 8; ++i) {
        int id = t + 256 * i, c = id >> 4, p4 = (id & 15) * 4;
        float4 v = { ll[c * 65 + p4], ll[c * 65 + p4 + 1],
                     ll[c * 65 + p4 + 2], ll[c * 65 + p4 + 3] };
        *reinterpret_cast<float4*>(&outp[(size_t)b * CH * HW + (size_t)c * HW + hw0 + p4]) = v;
    }
}

// ---------------------------------------------------------------------------
// 6 dispatches. Quarters: ws W0..W3, d_out D0..D3.
//  1 qkv_self_b : in1->SA{q@W0,k@D0,v@D1}, in2->SB{q@W1,k@D2,v@D3}
//  2 attn5b(SA,SB): T_A@W0, T_B@W1 (in-place over q)
//  3 fcx_a (2GH): X1=LN(fc(T_A)+in1)@W2, X2@W3 (reads W0,W1; writes W2,W3)
//  4 fcx_b2 (6GH): reads ONLY W2,W3; writes C1{q@W0,k@D0,v@D1},
//    C2{q@W1,k@D2,v@D3} (T dead after step 3 -> no read/write overlap)
//  5 attn5b(C1,C2): T1@W0, T2@W1
//  6 ffn_ln_b: (T1@W0, X1@W2)->out1@(D0+D1 bytes); (T2@W1, X2@W3)->out2@(D2+D3)
//    All stream-ordered; no intra-dispatch races; written-before-read.
// ---------------------------------------------------------------------------
extern "C" void kernel_launch(void* const* d_in, const int* in_sizes, int n_in,
                              void* d_out, int out_size, void* d_ws, size_t ws_size,
                              hipStream_t stream) {
    (void)in_sizes; (void)n_in; (void)out_size; (void)ws_size;
    const float* in1  = (const float*)d_in[0];
    const float* in2  = (const float*)d_in[1];
    const float* wq_s = (const float*)d_in[2];
    const float* wk_s = (const float*)d_in[3];
    const float* wv_s = (const float*)d_in[4];
    const float* fc_s = (const float*)d_in[5];
    const float* lnw_s= (const float*)d_in[6];
    const float* lnb_s= (const float*)d_in[7];
    const float* wq_c = (const float*)d_in[8];
    const float* wk_c = (const float*)d_in[9];
    const float* wv_c = (const float*)d_in[10];
    const float* fc_c = (const float*)d_in[11];
    const float* lnw_c= (const float*)d_in[12];
    const float* lnb_c= (const float*)d_in[13];
    const float* w1   = (const float*)d_in[14];
    const float* b1   = (const float*)d_in[15];
    const float* w2   = (const float*)d_in[16];
    const float* b2   = (const float*)d_in[17];
    const float* lnw_f= (const float*)d_in[18];
    const float* lnb_f= (const float*)d_in[19];

    const size_t BUF  = (size_t)NPIX * CH;
    const size_t BUFB = BUF * 2;
    char* ws = (char*)d_ws;
    h16* W0 = (h16*)(ws + 0 * BUFB);
    h16* W1 = (h16*)(ws + 1 * BUFB);
    h16* W2 = (h16*)(ws + 2 * BUFB);
    h16* W3 = (h16*)(ws + 3 * BUFB);
    h16* D0 = (h16*)d_out;
    h16* D1 = (h16*)((char*)d_out + 1 * BUFB);
    h16* D2 = (h16*)((char*)d_out + 2 * BUFB);
    h16* D3 = (h16*)((char*)d_out + 3 * BUFB);
    float* out1 = (float*)d_out;
    float* out2 = (float*)d_out + BUF;

    const dim3 B(256);

    Set SA = {W0, D0, D1};
    Set SB = {W1, D2, D3};
    h16* X1 = W2;
    h16* X2 = W3;
    Set C1 = {W0, D0, D1};
    Set C2 = {W1, D2, D3};

    // 1: self QKV (batched, reg-prefetched W)
    qkv_self_b<<<dim3(2 * GH), B, 0, stream>>>(in1, in2, wq_s, wk_s, wv_s, SA, SB);
    // 2: self attention
    attn5b<<<dim3(2 * ATB), B, 0, stream>>>(SA, SB);
    // 3: self fc+LN -> X (1-GEMM chain)
    fcx_a<<<dim3(2 * GH), B, 0, stream>>>(SA.q, SB.q, in1, in2,
                                          fc_s, lnw_s, lnb_s, X1, X2);
    // 4: cross QKV, one GEMM per block (3x parallelism, 1 barrier)
    fcx_b2<<<dim3(6 * GH), B, 0, stream>>>(X1, X2, wq_c, wk_c, wv_c, C1, C2);
    // 5: cross attention
    attn5b<<<dim3(2 * ATB), B, 0, stream>>>(C1, C2);
    // 6: fused cross-fc+LN + FFN + final LN -> f32 outputs
    ffn_ln_b<<<dim3(2 * GH), B, 0, stream>>>(C1.q, C2.q, X1, X2,
                                             fc_c, lnw_c, lnb_c,
                                             w1, b1, w2, b2, lnw_f, lnb_f,
                                             out1, out2);
}

// Round 20
// 152.280 us; speedup vs baseline: 1.0258x; 1.0258x over previous
//
#include <hip/hip_runtime.h>
#include <hip/hip_bf16.h>

typedef _Float16 h16;
typedef __attribute__((ext_vector_type(8))) _Float16 f16x8v;   // 8 f16 (4 VGPR)
typedef __attribute__((ext_vector_type(2))) _Float16 h2v;      // packed pair
typedef __attribute__((ext_vector_type(4))) float f32x4;       // MFMA acc
#define DI __device__ __forceinline__

constexpr int CH = 128;
constexpr int HH = 96, WW = 96;
constexpr int HW = HH * WW;          // 9216
constexpr int NB = 4;
constexpr int NPIX = NB * HW;        // 36864
constexpr int LDT = 136;             // conv LDS row stride (elems)
constexpr size_t HP = (size_t)NPIX * 32;   // head-plane elements
constexpr int GH = NPIX / 64;        // 576 conv blocks per tensor
// attention tile geometry (r10 best-measured config)
constexpr int TY = 4, TX = 32;       // tile pixels
constexpr int HYH = TY + 4, HXH = TX + 4;  // halo 8 x 36
constexpr int LDC = 40;              // LDS ch stride
constexpr int ATB = NPIX / (TY * TX) * 4;  // 1152 attn blocks per set

struct __attribute__((aligned(16))) h16x8 { h16 h[8]; };
struct Set { h16 *q, *k, *v; };      // comp-plane bases, each [4][NPIX][32]

DI float h2f(h16 x) { return (float)x; }
DI h16   f2h(float x) { return (h16)x; }

// ---- staging helpers (256 thr) --------------------------------------------

// planar f32 [c][HW] -> LDS tile [px][c] f16
DI void stage_x_pl(const float* __restrict__ src, h16* xl, int t) {
    #pragma unroll
    for (int i = 0; i < 8; ++i) {
        int id = t + 256 * i, c = id >> 4, p4 = (id & 15) * 4;
        float4 v = *reinterpret_cast<const float4*>(&src[(size_t)c * HW + p4]);
        xl[(p4 + 0) * LDT + c] = f2h(v.x);
        xl[(p4 + 1) * LDT + c] = f2h(v.y);
        xl[(p4 + 2) * LDT + c] = f2h(v.z);
        xl[(p4 + 3) * LDT + c] = f2h(v.w);
    }
}

// head-major T [h][p][32] -> LDS tile [px][128]
DI void stage_x_hm(const h16* __restrict__ Tq, h16* xl, int p0, int t) {
    const int px = t >> 2, c8 = (t & 3) * 8;
    #pragma unroll
    for (int h = 0; h < 4; ++h)
        *reinterpret_cast<f16x8v*>(&xl[px * LDT + h * 32 + c8]) =
            *reinterpret_cast<const f16x8v*>(&Tq[(size_t)h * HP + (size_t)(p0 + px) * 32 + c8]);
}

DI void stage_w(const float* __restrict__ w, h16* wl, int t) {
    #pragma unroll
    for (int i = 0; i < 8; ++i) {
        int id = t + 256 * i, o = id >> 4, cc = (id & 15) * 8;
        float4 a = *reinterpret_cast<const float4*>(&w[o * CH + cc]);
        float4 b = *reinterpret_cast<const float4*>(&w[o * CH + cc + 4]);
        h16x8 tmp;
        tmp.h[0] = f2h(a.x); tmp.h[1] = f2h(a.y); tmp.h[2] = f2h(a.z); tmp.h[3] = f2h(a.w);
        tmp.h[4] = f2h(b.x); tmp.h[5] = f2h(b.y); tmp.h[6] = f2h(b.z); tmp.h[7] = f2h(b.w);
        *reinterpret_cast<f16x8v*>(&wl[o * LDT + cc]) = *reinterpret_cast<const f16x8v*>(&tmp);
    }
}

// register-prefetch version of stage_w: issue loads + cvt into 32 VGPRs
DI void wload(const float* __restrict__ w, f16x8v* pre, int t) {
    #pragma unroll
    for (int i = 0; i < 8; ++i) {
        int id = t + 256 * i, o = id >> 4, cc = (id & 15) * 8;
        float4 a = *reinterpret_cast<const float4*>(&w[o * CH + cc]);
        float4 b = *reinterpret_cast<const float4*>(&w[o * CH + cc + 4]);
        h16x8 tmp;
        tmp.h[0] = f2h(a.x); tmp.h[1] = f2h(a.y); tmp.h[2] = f2h(a.z); tmp.h[3] = f2h(a.w);
        tmp.h[4] = f2h(b.x); tmp.h[5] = f2h(b.y); tmp.h[6] = f2h(b.z); tmp.h[7] = f2h(b.w);
        pre[i] = *reinterpret_cast<const f16x8v*>(&tmp);
    }
}
DI void wcommit(const f16x8v* pre, h16* wl, int t) {
    #pragma unroll
    for (int i = 0; i < 8; ++i) {
        int id = t + 256 * i, o = id >> 4, cc = (id & 15) * 8;
        *reinterpret_cast<f16x8v*>(&wl[o * LDT + cc]) = pre[i];
    }
}

// resid tile prefetch: planar f32 -> 8 float4 regs -> rl[c][65]
DI void rload(const float* __restrict__ src, float4* rpre, int t) {
    #pragma unroll
    for (int i = 0; i < 8; ++i) {
        int id = t + 256 * i, c = id >> 4, p4 = (id & 15) * 4;
        rpre[i] = *reinterpret_cast<const float4*>(&src[(size_t)c * HW + p4]);
    }
}
DI void rcommit(const float4* rpre, float* rl, int t) {
    #pragma unroll
    for (int i = 0; i < 8; ++i) {
        int id = t + 256 * i, c = id >> 4, p4 = (id & 15) * 4;
        rl[c * 65 + p4 + 0] = rpre[i].x;
        rl[c * 65 + p4 + 1] = rpre[i].y;
        rl[c * 65 + p4 + 2] = rpre[i].z;
        rl[c * 65 + p4 + 3] = rpre[i].w;
    }
}

DI void gemm64(const h16* xl, const h16* wl, int w, int l, f32x4* acc) {
    const int s = l & 15, g = l >> 4;
    #pragma unroll
    for (int ks = 0; ks < 4; ++ks) {
        f16x8v a = *reinterpret_cast<const f16x8v*>(&xl[(16 * w + s) * LDT + ks * 32 + g * 8]);
        #pragma unroll
        for (int n = 0; n < 8; ++n) {
            f16x8v b = *reinterpret_cast<const f16x8v*>(&wl[(16 * n + s) * LDT + ks * 32 + g * 8]);
            acc[n] = __builtin_amdgcn_mfma_f32_16x16x32_f16(a, b, acc[n], 0, 0, 0);
        }
    }
}

// epilogue into head-major comp plane [head][p][32]
DI void qkv_epi(const f32x4* acc, h16* comp, int p0, int w, int l) {
    const int s = l & 15, g = l >> 4;
    #pragma unroll
    for (int n = 0; n < 8; ++n) {
        const int o = 16 * n + s, head = o >> 5, ch = o & 31;
        h16* pl = comp + (size_t)head * HP;
        #pragma unroll
        for (int j = 0; j < 4; ++j) {
            int px = 16 * w + 4 * g + j;
            pl[(size_t)(p0 + px) * 32 + ch] = f2h(acc[n][j]);
        }
    }
}

// in-wave channel LayerNorm on r[8][4]; lanes sharing (l>>4) hold all 128 o.
DI void ln128(float r[8][4], const float* gm, const float* bt, float val[8][4]) {
    #pragma unroll
    for (int j = 0; j < 4; ++j) {
        float sm = 0.f, sq = 0.f;
        #pragma unroll
        for (int n = 0; n < 8; ++n) { float v = r[n][j]; sm += v; sq += v * v; }
        sm += __shfl_xor(sm, 1); sq += __shfl_xor(sq, 1);
        sm += __shfl_xor(sm, 2); sq += __shfl_xor(sq, 2);
        sm += __shfl_xor(sm, 4); sq += __shfl_xor(sq, 4);
        sm += __shfl_xor(sm, 8); sq += __shfl_xor(sq, 8);
        const float mu = sm * (1.f / 128.f);
        const float var = sq * (1.f / 128.f) - mu * mu;
        const float rs = rsqrtf(var + 1e-6f);
        #pragma unroll
        for (int n = 0; n < 8; ++n)
            val[n][j] = gm[n] * (r[n][j] - mu) * rs + bt[n];
    }
}

// ---- batched self-attn QKV (256 thr, reg-prefetched W) --------------------
__global__ __launch_bounds__(256, 2)
void qkv_self_b(const float* __restrict__ x0, const float* __restrict__ x1,
                const float* __restrict__ w0, const float* __restrict__ w1_,
                const float* __restrict__ w2_, Set sA, Set sB) {
    __shared__ h16 xl[64 * LDT];
    __shared__ h16 wl[CH * LDT];
    const int bid = blockIdx.x, half = bid / GH, p0 = (bid % GH) * 64;
    const float* xv = half ? x1 : x0;
    Set S = half ? sB : sA;
    const int t = threadIdx.x;
    const int b = p0 / HW, hw0 = p0 % HW;
    stage_x_pl(xv + (size_t)b * CH * HW + hw0, xl, t);
    stage_w(w0, wl, t);
    __syncthreads();
    const int w = t >> 6, l = t & 63;

    f16x8v pre[8];
    #pragma unroll
    for (int m = 0; m < 3; ++m) {
        h16* comp = (m == 0) ? S.q : ((m == 1) ? S.k : S.v);
        if (m == 0) wload(w1_, pre, t);        // in flight during gemm
        if (m == 1) wload(w2_, pre, t);
        f32x4 acc[8];
        #pragma unroll
        for (int n = 0; n < 8; ++n) acc[n] = {0.f, 0.f, 0.f, 0.f};
        gemm64(xl, wl, w, l, acc);
        qkv_epi(acc, comp, p0, w, l);
        if (m < 2) {
            __syncthreads();                   // wl reads done
            wcommit(pre, wl, t);
            __syncthreads();                   // wl ready
        }
    }
}

// ---- 5x5 local attention (batched over 2 sets) — r10 best config ----------
__global__ __launch_bounds__(256)
void attn5b(Set s0, Set s1) {
    __shared__ h16 kv[HYH * HXH * LDC];          // 23 KB, reused K then V
    const int bid = blockIdx.x, setId = bid / ATB, id = bid - setId * ATB;
    Set S = setId ? s1 : s0;
    const int n = id & 3, tile = id >> 2;
    const int img = tile / 72, rem = tile % 72, tr = rem / 3, tc = rem % 3;
    const int y0 = tr * TY, x0 = tc * TX;
    const int t = threadIdx.x;
    const int p = t >> 1, half = t & 1, ch16 = half * 16;
    const int ty = p >> 5, tx = p & 31;
    h16* Qh = S.q + (size_t)n * HP;
    const h16* Kh = S.k + (size_t)n * HP;
    const h16* Vh = S.v + (size_t)n * HP;
    const int gp = img * HW + (y0 + ty) * WW + (x0 + tx);
    h16* qp = Qh + (size_t)gp * 32 + ch16;

    f16x8v q0 = *reinterpret_cast<const f16x8v*>(qp);
    f16x8v q1 = *reinterpret_cast<const f16x8v*>(qp + 8);
    {
        const h16 sc = (h16)0.17677669529663689f;
        #pragma unroll
        for (int e = 0; e < 8; ++e) { q0[e] *= sc; q1[e] *= sc; }
    }

    #pragma unroll
    for (int i = 0; i < 5; ++i) {
        int id2 = t + 256 * i;
        if (id2 < 1152) {
            int r = id2 / 144, c = id2 - r * 144, px = c >> 2, c8 = (c & 3) * 8;
            int y = y0 + r - 2, x = x0 + px - 2;
            f16x8v v = {0, 0, 0, 0, 0, 0, 0, 0};
            if ((unsigned)y < (unsigned)HH && (unsigned)x < (unsigned)WW)
                v = *reinterpret_cast<const f16x8v*>(&Kh[((size_t)(img * HW + y * WW + x)) * 32 + c8]);
            *reinterpret_cast<f16x8v*>(&kv[(r * HXH + px) * LDC + c8]) = v;
        }
    }
    __syncthreads();

    float corr[25];
    #pragma unroll
    for (int dy = 0; dy < 5; ++dy)
        #pragma unroll
        for (int dx = 0; dx < 5; ++dx) {
            const h16* kp = &kv[((ty + dy) * HXH + tx + dx) * LDC + ch16];
            f16x8v k0 = *reinterpret_cast<const f16x8v*>(kp);
            f16x8v k1 = *reinterpret_cast<const f16x8v*>(kp + 8);
            float s;
#if __has_builtin(__builtin_amdgcn_fdot2)
            s = __builtin_amdgcn_fdot2(h2v{q0[0], q0[1]}, h2v{k0[0], k0[1]}, 0.f, false);
            s = __builtin_amdgcn_fdot2(h2v{q0[2], q0[3]}, h2v{k0[2], k0[3]}, s, false);
            s = __builtin_amdgcn_fdot2(h2v{q0[4], q0[5]}, h2v{k0[4], k0[5]}, s, false);
            s = __builtin_amdgcn_fdot2(h2v{q0[6], q0[7]}, h2v{k0[6], k0[7]}, s, false);
            s = __builtin_amdgcn_fdot2(h2v{q1[0], q1[1]}, h2v{k1[0], k1[1]}, s, false);
            s = __builtin_amdgcn_fdot2(h2v{q1[2], q1[3]}, h2v{k1[2], k1[3]}, s, false);
            s = __builtin_amdgcn_fdot2(h2v{q1[4], q1[5]}, h2v{k1[4], k1[5]}, s, false);
            s = __builtin_amdgcn_fdot2(h2v{q1[6], q1[7]}, h2v{k1[6], k1[7]}, s, false);
#else
            s = 0.f;
            #pragma unroll
            for (int e = 0; e < 8; ++e) s += h2f(q0[e]) * h2f(k0[e]);
            #pragma unroll
            for (int e = 0; e < 8; ++e) s += h2f(q1[e]) * h2f(k1[e]);
#endif
            s += __shfl_xor(s, 1);
            corr[dy * 5 + dx] = s;
        }

    float m = corr[0];
    #pragma unroll
    for (int j = 1; j < 25; ++j) m = fmaxf(m, corr[j]);
    float sum = 0.f;
    #pragma unroll
    for (int j = 0; j < 25; ++j) {
        float e = __expf(corr[j] - m);
        corr[j] = e; sum += e;
    }
    const float inv = 1.f / sum;

    __syncthreads();                               // all K reads done
    #pragma unroll
    for (int i = 0; i < 5; ++i) {
        int id2 = t + 256 * i;
        if (id2 < 1152) {
            int r = id2 / 144, c = id2 - r * 144, px = c >> 2, c8 = (c & 3) * 8;
            int y = y0 + r - 2, x = x0 + px - 2;
            f16x8v v = {0, 0, 0, 0, 0, 0, 0, 0};
            if ((unsigned)y < (unsigned)HH && (unsigned)x < (unsigned)WW)
                v = *reinterpret_cast<const f16x8v*>(&Vh[((size_t)(img * HW + y * WW + x)) * 32 + c8]);
            *reinterpret_cast<f16x8v*>(&kv[(r * HXH + px) * LDC + c8]) = v;
        }
    }
    __syncthreads();

    f16x8v o0 = {0, 0, 0, 0, 0, 0, 0, 0};
    f16x8v o1 = {0, 0, 0, 0, 0, 0, 0, 0};
    #pragma unroll
    for (int dy = 0; dy < 5; ++dy)
        #pragma unroll
        for (int dx = 0; dx < 5; ++dx) {
            const h16 ah = f2h(corr[dy * 5 + dx]);
            const f16x8v av = {ah, ah, ah, ah, ah, ah, ah, ah};
            const h16* vp = &kv[((ty + dy) * HXH + tx + dx) * LDC + ch16];
            f16x8v v0 = *reinterpret_cast<const f16x8v*>(vp);
            f16x8v v1 = *reinterpret_cast<const f16x8v*>(vp + 8);
            o0 += av * v0;                       // v_pk_fma_f16
            o1 += av * v1;
        }
    {
        const h16 ih = f2h(inv);
        const f16x8v iv = {ih, ih, ih, ih, ih, ih, ih, ih};
        o0 *= iv; o1 *= iv;
    }
    *reinterpret_cast<f16x8v*>(qp)     = o0;
    *reinterpret_cast<f16x8v*>(qp + 8) = o1;
}

// ---- FUSED (256 thr, reg-prefetched W + resid): fc+LN + cross-QKV ---------
// q -> OWN cross set; k,v -> OTHER cross set (C1.kv=f(X2), C2.kv=f(X1)).
__global__ __launch_bounds__(256, 2)
void fcx1_b(const h16* __restrict__ tA, const h16* __restrict__ tB,
            const float* __restrict__ in1, const float* __restrict__ in2,
            const float* __restrict__ wfc, const float* __restrict__ gamma,
            const float* __restrict__ beta,
            const float* __restrict__ wq, const float* __restrict__ wk,
            const float* __restrict__ wv,
            h16* __restrict__ x1g, h16* __restrict__ x2g, Set c1, Set c2) {
    __shared__ h16 xl[64 * LDT];
    __shared__ __align__(16) char wsm[CH * LDT * 2];   // wl (h16) | rl (f32 [128][65])
    h16*   wl = (h16*)wsm;
    float* rl = (float*)wsm;
    const int bid = blockIdx.x, half = bid / GH, p0 = (bid % GH) * 64;
    const h16*   tin = half ? tB : tA;
    const float* inr = half ? in2 : in1;
    h16*         xg  = half ? x2g : x1g;
    Set own   = half ? c2 : c1;
    Set other = half ? c1 : c2;
    const int t = threadIdx.x;
    const int w = t >> 6, l = t & 63, s = l & 15, g4 = l >> 4;
    const int b = p0 / HW, hw0 = p0 % HW;

    stage_x_hm(tin, xl, p0, t);
    stage_w(wfc, wl, t);
    float4 rpre[8];
    rload(inr + (size_t)b * CH * HW + hw0, rpre, t);   // resid in flight
    __syncthreads();

    // fc GEMM (resid loads in flight underneath)
    f32x4 accF[8];
    #pragma unroll
    for (int n = 0; n < 8; ++n) accF[n] = {0.f, 0.f, 0.f, 0.f};
    gemm64(xl, wl, w, l, accF);
    __syncthreads();                 // wl (wfc) reads done -> rl may overwrite

    rcommit(rpre, rl, t);
    f16x8v pre[8];
    wload(wq, pre, t);               // wq in flight during LN
    __syncthreads();                 // rl visible

    // X = LN(fc(T) + resid)
    h16 vX[8][4];
    {
        float gm[8], bt[8], r[8][4], val[8][4];
        #pragma unroll
        for (int n = 0; n < 8; ++n) { gm[n] = gamma[16 * n + s]; bt[n] = beta[16 * n + s]; }
        #pragma unroll
        for (int n = 0; n < 8; ++n) {
            const int o = 16 * n + s;
            #pragma unroll
            for (int j = 0; j < 4; ++j) {
                const int px = 16 * w + 4 * g4 + j;
                r[n][j] = accF[n][j] + rl[o * 65 + px];
            }
        }
        ln128(r, gm, bt, val);
        #pragma unroll
        for (int n = 0; n < 8; ++n)
            #pragma unroll
            for (int j = 0; j < 4; ++j) vX[n][j] = f2h(val[n][j]);
    }
    __syncthreads();                 // rl reads done -> wl may overwrite
    // X -> LDS (overwrite T tile) + global (resid for final stage)
    #pragma unroll
    for (int n = 0; n < 8; ++n) {
        const int o = 16 * n + s;
        #pragma unroll
        for (int j = 0; j < 4; ++j) {
            const int px = 16 * w + 4 * g4 + j;
            xl[px * LDT + o] = vX[n][j];
            xg[(size_t)(p0 + px) * CH + o] = vX[n][j];
        }
    }
    wcommit(pre, wl, t);             // wq -> wl
    __syncthreads();
    {
        f32x4 acc[8];
        #pragma unroll
        for (int n = 0; n < 8; ++n) acc[n] = {0.f, 0.f, 0.f, 0.f};
        wload(wk, pre, t);           // wk in flight during q GEMM
        gemm64(xl, wl, w, l, acc);
        qkv_epi(acc, own.q, p0, w, l);
    }
    __syncthreads();
    wcommit(pre, wl, t);
    __syncthreads();
    {
        f32x4 acc[8];
        #pragma unroll
        for (int n = 0; n < 8; ++n) acc[n] = {0.f, 0.f, 0.f, 0.f};
        wload(wv, pre, t);           // wv in flight during k GEMM
        gemm64(xl, wl, w, l, acc);
        qkv_epi(acc, other.k, p0, w, l);
    }
    __syncthreads();
    wcommit(pre, wl, t);
    __syncthreads();
    {
        f32x4 acc[8];
        #pragma unroll
        for (int n = 0; n < 8; ++n) acc[n] = {0.f, 0.f, 0.f, 0.f};
        gemm64(xl, wl, w, l, acc);
        qkv_epi(acc, other.v, p0, w, l);
    }
}

// ---- FUSED: fc+LN (cross) + full FFN + final LN -> planar f32 out ---------
__global__ __launch_bounds__(256, 2)
void ffn_ln_b(const h16* __restrict__ t0, const h16* __restrict__ t1,
              const h16* __restrict__ x0, const h16* __restrict__ x1,
              const float* __restrict__ wfc, const float* __restrict__ gc,
              const float* __restrict__ bc,
              const float* __restrict__ w1m, const float* __restrict__ b1v,
              const float* __restrict__ w2m, const float* __restrict__ b2v,
              const float* __restrict__ gf, const float* __restrict__ bf,
              float* __restrict__ o0, float* __restrict__ o1) {
    __shared__ __align__(16) char smem[64 * LDT * 2 * 2 + CH * LDT * 2]; // 69632 B
    h16*   xl = (h16*)smem;                        // T stage, later h tile
    h16*   yl = (h16*)(smem + 64 * LDT * 2);       // Y tile (resid)
    h16*   wl = (h16*)(smem + 64 * LDT * 2 * 2);   // fc_c, W1, W2 in turn
    float* ll = (float*)(smem + 64 * LDT * 2 * 2); // out bounce (aliases wl)
    const int bid = blockIdx.x, half = bid / GH, p0 = (bid % GH) * 64;
    const h16* tin = half ? t1 : t0;
    const h16* xg  = half ? x1 : x0;
    float* outp = half ? o1 : o0;
    const int t = threadIdx.x;
    const int w = t >> 6, l = t & 63, s = l & 15, g4 = l >> 4;

    stage_x_hm(tin, xl, p0, t);
    stage_w(wfc, wl, t);
    __syncthreads();

    // Y = LN(fc(T) + X)
    h16 yv[8][4];
    {
        f32x4 acc[8];
        #pragma unroll
        for (int n = 0; n < 8; ++n) acc[n] = {0.f, 0.f, 0.f, 0.f};
        gemm64(xl, wl, w, l, acc);
        float gm[8], bt[8], r[8][4], val[8][4];
        #pragma unroll
        for (int n = 0; n < 8; ++n) { gm[n] = gc[16 * n + s]; bt[n] = bc[16 * n + s]; }
        #pragma unroll
        for (int n = 0; n < 8; ++n) {
            const int o = 16 * n + s;
            #pragma unroll
            for (int j = 0; j < 4; ++j) {
                const int px = 16 * w + 4 * g4 + j;
                r[n][j] = acc[n][j] + h2f(xg[(size_t)(p0 + px) * CH + o]);
            }
        }
        ln128(r, gm, bt, val);
        #pragma unroll
        for (int n = 0; n < 8; ++n)
            #pragma unroll
            for (int j = 0; j < 4; ++j) yv[n][j] = f2h(val[n][j]);
    }
    __syncthreads();                 // xl/wl gemm reads done
    #pragma unroll
    for (int n = 0; n < 8; ++n) {
        const int o = 16 * n + s;
        #pragma unroll
        for (int j = 0; j < 4; ++j)
            yl[(16 * w + 4 * g4 + j) * LDT + o] = yv[n][j];
    }
    stage_w(w1m, wl, t);
    __syncthreads();

    // h = relu(W1 Y + b1) -> hl (reuses xl)
    {
        f32x4 acc[8];
        #pragma unroll
        for (int n = 0; n < 8; ++n) acc[n] = {0.f, 0.f, 0.f, 0.f};
        gemm64(yl, wl, w, l, acc);
        #pragma unroll
        for (int n = 0; n < 8; ++n) {
            const int o = 16 * n + s;
            const float bv = b1v[o];
            #pragma unroll
            for (int j = 0; j < 4; ++j)
                xl[(16 * w + 4 * g4 + j) * LDT + o] = f2h(fmaxf(acc[n][j] + bv, 0.f));
        }
    }
    __syncthreads();                 // wl gemm reads + hl writes done
    stage_w(w2m, wl, t);
    __syncthreads();

    // out = LN2(W2 h + b2) + Y
    float val[8][4];
    {
        f32x4 acc[8];
        #pragma unroll
        for (int n = 0; n < 8; ++n) acc[n] = {0.f, 0.f, 0.f, 0.f};
        gemm64(xl, wl, w, l, acc);
        float gm[8], bt[8], r[8][4];
        #pragma unroll
        for (int n = 0; n < 8; ++n) { gm[n] = gf[16 * n + s]; bt[n] = bf[16 * n + s]; }
        #pragma unroll
        for (int n = 0; n < 8; ++n) {
            const int o = 16 * n + s;
            const float bv = b2v[o];
            #pragma unroll
            for (int j = 0; j < 4; ++j) r[n][j] = acc[n][j] + bv;
        }
        ln128(r, gm, bt, val);
        #pragma unroll
        for (int n = 0; n < 8; ++n) {
            const int o = 16 * n + s;
            #pragma unroll
            for (int j = 0; j < 4; ++j)
                val[n][j] += h2f(yl[(16 * w + 4 * g4 + j) * LDT + o]);
        }
    }
    __syncthreads();                 // wl(gemm3)/yl reads done -> ll may alias
    #pragma unroll
    for (int n = 0; n < 8; ++n) {
        const int o = 16 * n + s;
        #pragma unroll
        for (int j = 0; j < 4; ++j) ll[o * 65 + 16 * w + 4 * g4 + j] = val[n][j];
    }
    __syncthreads();
    const int b = p0 / HW, hw0 = p0 % HW;
    #pragma unroll
    for (int i = 0; i < 8; ++i) {
        int id = t + 256 * i, c = id >> 4, p4 = (id & 15) * 4;
        float4 v = { ll[c * 65 + p4], ll[c * 65 + p4 + 1],
                     ll[c * 65 + p4 + 2], ll[c * 65 + p4 + 3] };
        *reinterpret_cast<float4*>(&outp[(size_t)b * CH * HW + (size_t)c * HW + hw0 + p4]) = v;
    }
}

// ---------------------------------------------------------------------------
// 5 dispatches. Quarters: ws W0..W3, d_out D0..D3.
//  1 qkv_self_b : in1->SA{q@W0,k@D0,v@D1}, in2->SB{q@W1,k@D2,v@D3}
//  2 attn5b(SA,SB): T_A@W0, T_B@W1 (in-place over q)
//  3 fcx1_b (2xGH blocks): per-tensor X=LN(fc(T)+in) -> X1@W2/X2@W3 (LDS+glob);
//    q->own set, k/v->other set: C1{q@W0,k@D0,v@D1}, C2{q@W1,k@D2,v@D3}
//  4 attn5b(C1,C2): T1@W0, T2@W1
//  5 ffn_ln_b: (T1@W0, X1@W2)->out1@(D0+D1 bytes); (T2@W1, X2@W3)->out2@(D2+D3)
//    Step-5 reads only ws; writes only d_out (all quarters dead). No races.
// ---------------------------------------------------------------------------
extern "C" void kernel_launch(void* const* d_in, const int* in_sizes, int n_in,
                              void* d_out, int out_size, void* d_ws, size_t ws_size,
                              hipStream_t stream) {
    (void)in_sizes; (void)n_in; (void)out_size; (void)ws_size;
    const float* in1  = (const float*)d_in[0];
    const float* in2  = (const float*)d_in[1];
    const float* wq_s = (const float*)d_in[2];
    const float* wk_s = (const float*)d_in[3];
    const float* wv_s = (const float*)d_in[4];
    const float* fc_s = (const float*)d_in[5];
    const float* lnw_s= (const float*)d_in[6];
    const float* lnb_s= (const float*)d_in[7];
    const float* wq_c = (const float*)d_in[8];
    const float* wk_c = (const float*)d_in[9];
    const float* wv_c = (const float*)d_in[10];
    const float* fc_c = (const float*)d_in[11];
    const float* lnw_c= (const float*)d_in[12];
    const float* lnb_c= (const float*)d_in[13];
    const float* w1   = (const float*)d_in[14];
    const float* b1   = (const float*)d_in[15];
    const float* w2   = (const float*)d_in[16];
    const float* b2   = (const float*)d_in[17];
    const float* lnw_f= (const float*)d_in[18];
    const float* lnb_f= (const float*)d_in[19];

    const size_t BUF  = (size_t)NPIX * CH;
    const size_t BUFB = BUF * 2;
    char* ws = (char*)d_ws;
    h16* W0 = (h16*)(ws + 0 * BUFB);
    h16* W1 = (h16*)(ws + 1 * BUFB);
    h16* W2 = (h16*)(ws + 2 * BUFB);
    h16* W3 = (h16*)(ws + 3 * BUFB);
    h16* D0 = (h16*)d_out;
    h16* D1 = (h16*)((char*)d_out + 1 * BUFB);
    h16* D2 = (h16*)((char*)d_out + 2 * BUFB);
    h16* D3 = (h16*)((char*)d_out + 3 * BUFB);
    float* out1 = (float*)d_out;
    float* out2 = (float*)d_out + BUF;

    const dim3 B(256);

    Set SA = {W0, D0, D1};
    Set SB = {W1, D2, D3};
    h16* X1 = W2;
    h16* X2 = W3;
    Set C1 = {W0, D0, D1};
    Set C2 = {W1, D2, D3};

    // 1: self QKV (batched, reg-prefetched W)
    qkv_self_b<<<dim3(2 * GH), B, 0, stream>>>(in1, in2, wq_s, wk_s, wv_s, SA, SB);
    // 2: self attention
    attn5b<<<dim3(2 * ATB), B, 0, stream>>>(SA, SB);
    // 3: fused self-fc+LN + cross QKV (reg-prefetched W + resid)
    fcx1_b<<<dim3(2 * GH), B, 0, stream>>>(SA.q, SB.q, in1, in2,
                                           fc_s, lnw_s, lnb_s,
                                           wq_c, wk_c, wv_c, X1, X2, C1, C2);
    // 4: cross attention
    attn5b<<<dim3(2 * ATB), B, 0, stream>>>(C1, C2);
    // 5: fused cross-fc+LN + FFN + final LN -> f32 outputs
    ffn_ln_b<<<dim3(2 * GH), B, 0, stream>>>(C1.q, C2.q, X1, X2,
                                             fc_c, lnw_c, lnb_c,
                                             w1, b1, w2, b2, lnw_f, lnb_f,
                                             out1, out2);
}